// Round 1
// baseline (308.956 us; speedup 1.0000x reference)
//
#include <hip/hip_runtime.h>

#define B 128
#define S 512
#define T 64

// One wave (64 lanes) per batch element. Lane j owns tag j.
// alpha recursion in log space, but the per-step LSE is computed as a
// plain matvec against E = exp(transitions) held in registers (lane j
// holds column j of E). Only 1 exp + 1 log per lane per step.
__global__ __launch_bounds__(64)
void crf_fwd(const float* __restrict__ features,
             const int*   __restrict__ labels,
             const float* __restrict__ mask,
             const float* __restrict__ transitions,
             float*       __restrict__ ws)
{
    __shared__ float trans_lds[T * T];
    __shared__ float ea_lds[2][T];

    const int lane = threadIdx.x;   // tag index j
    const int b    = blockIdx.x;    // batch element

    // Stage raw transitions into LDS (coalesced), used for gold gathers.
    for (int i = 0; i < T; ++i)
        trans_lds[i * T + lane] = transitions[i * T + lane];
    __syncthreads();

    // E column for this lane: etr[i] = exp(trans[i][lane]). Fully unrolled
    // so the array stays in VGPRs (64 regs).
    float etr[T];
    #pragma unroll
    for (int i = 0; i < T; ++i)
        etr[i] = __expf(trans_lds[i * T + lane]);

    const float* fb = features + (size_t)b * S * T;
    const float* mb = mask + (size_t)b * S;
    const int*   lb = labels + (size_t)b * S;

    // t = 0
    float alpha    = fb[lane];          // emissions[b,0,lane]
    int   lab_prev = lb[0];
    float m_prev   = mb[0];
    float gold     = __shfl(alpha, lab_prev) * m_prev;

    for (int t = 1; t < S; ++t) {
        float em  = fb[t * T + lane];   // coalesced 256B per wave
        float m_t = mb[t];
        int   lab = lb[t];

        // ---- gold score (all lanes compute redundantly) ----
        gold += __shfl(em, lab) * m_t;
        gold += trans_lds[lab_prev * T + lab] * (m_prev * m_t);
        lab_prev = lab;
        m_prev   = m_t;

        // ---- wave max of alpha (stability offset) ----
        float M = alpha;
        #pragma unroll
        for (int off = 32; off > 0; off >>= 1)
            M = fmaxf(M, __shfl_xor(M, off));

        // ---- exp-space matvec: s[j] = sum_i exp(alpha_i - M) * E[i][j] ----
        float ea = __expf(alpha - M);
        const int buf = t & 1;
        ea_lds[buf][lane] = ea;
        __syncthreads();

        const float4* ea4 = (const float4*)ea_lds[buf];
        float a0 = 0.f, a1 = 0.f, a2 = 0.f, a3 = 0.f;
        #pragma unroll
        for (int k = 0; k < T / 4; ++k) {
            float4 v = ea4[k];          // uniform broadcast ds_read_b128
            a0 += v.x * etr[4 * k + 0];
            a1 += v.y * etr[4 * k + 1];
            a2 += v.z * etr[4 * k + 2];
            a3 += v.w * etr[4 * k + 3];
        }
        float s = (a0 + a1) + (a2 + a3);

        float val = M + __logf(s) + em;      // log(0) = -inf on PAD column
        val = fmaxf(val, -1e30f);            // keep finite so blend can't NaN
        alpha = val * m_t + alpha * (1.0f - m_t);
    }

    // ---- logZ = logsumexp over lanes ----
    float M2 = alpha;
    #pragma unroll
    for (int off = 32; off > 0; off >>= 1)
        M2 = fmaxf(M2, __shfl_xor(M2, off));
    float e2 = __expf(alpha - M2);
    #pragma unroll
    for (int off = 32; off > 0; off >>= 1)
        e2 += __shfl_xor(e2, off);
    float logZ = M2 + __logf(e2);

    if (lane == 0)
        ws[b] = logZ - gold;
}

// Deterministic final mean over B=128 per-batch results.
__global__ __launch_bounds__(128)
void crf_reduce(const float* __restrict__ ws, float* __restrict__ out)
{
    const int tid = threadIdx.x;
    float v = ws[tid];
    #pragma unroll
    for (int off = 32; off > 0; off >>= 1)
        v += __shfl_xor(v, off);

    __shared__ float partial[2];
    if ((tid & 63) == 0)
        partial[tid >> 6] = v;
    __syncthreads();
    if (tid == 0)
        out[0] = (partial[0] + partial[1]) * (1.0f / (float)B);
}

extern "C" void kernel_launch(void* const* d_in, const int* in_sizes, int n_in,
                              void* d_out, int out_size, void* d_ws, size_t ws_size,
                              hipStream_t stream)
{
    const float* features    = (const float*)d_in[0]; // (B,S,T) f32
    const int*   labels      = (const int*)  d_in[1]; // (B,S) int
    const float* mask        = (const float*)d_in[2]; // (B,S) f32
    const float* transitions = (const float*)d_in[3]; // (T,T) f32
    float* out = (float*)d_out;
    float* ws  = (float*)d_ws;   // needs B floats

    crf_fwd<<<dim3(B), dim3(64), 0, stream>>>(features, labels, mask, transitions, ws);
    crf_reduce<<<dim3(1), dim3(128), 0, stream>>>(ws, out);
}

// Round 2
// 189.586 us; speedup vs baseline: 1.6296x; 1.6296x over previous
//
#include <hip/hip_runtime.h>

#define B 128
#define S 512
#define T 64

typedef float f2 __attribute__((ext_vector_type(2)));

// One wave (64 lanes) per batch element. Lane j owns tag j.
// Per-step LSE computed as exp-space matvec against E = exp(transitions)
// held in registers (lane j holds column j of E as 32 float2).
// Normalizer M = lane 1's alpha via v_readlane (no wave reduce).
// No __syncthreads in the hot loop: single-wave block, explicit
// s_waitcnt lgkmcnt(0) orders the LDS broadcast; global prefetches stay
// in flight (vmcnt never drained per step).
__global__ __launch_bounds__(64)
void crf_fwd(const float* __restrict__ features,
             const int*   __restrict__ labels,
             const float* __restrict__ mask,
             const float* __restrict__ transitions,
             float*       __restrict__ ws)
{
    __shared__ float trans_lds[T * T];
    __shared__ float ea_lds[2][T];

    const int lane = threadIdx.x;   // tag index j
    const int b    = blockIdx.x;    // batch element

    // Stage raw transitions (for gold gathers + etr init).
    for (int i = 0; i < T; ++i)
        trans_lds[i * T + lane] = transitions[i * T + lane];
    __syncthreads();

    // etr2[k] = (E[2k][lane], E[2k+1][lane]), E = exp(W). 32 float2 = 64 VGPR.
    f2 etr2[T / 2];
    #pragma unroll
    for (int k = 0; k < T / 2; ++k) {
        etr2[k].x = __expf(trans_lds[(2 * k + 0) * T + lane]);
        etr2[k].y = __expf(trans_lds[(2 * k + 1) * T + lane]);
    }

    const float* fb = features + (size_t)b * S * T;
    const float* mb = mask + (size_t)b * S;
    const int*   lb = labels + (size_t)b * S;

    // t = 0
    float alpha     = fb[lane];
    float gold_part = 0.f;

    // em prefetch pipeline, depth 2 (vector loads -> vmcnt, not lgkm)
    float em_n1 = fb[1 * T + lane];
    float em_n2 = fb[2 * T + lane];

    for (int c = 0; c < S / T; ++c) {
        const int base = c * T;
        const int tt   = base + lane;        // this lane's gold timestep

        // ---- gold partials for this chunk (issued once per 64 steps,
        //      latency hidden under the alpha chain) ----
        const int tm1   = tt > 0 ? tt - 1 : 0;
        int   lab_t = lb[tt];
        int   lab_p = lb[tm1];
        float mt    = mb[tt];
        float mp    = mb[tm1];
        float valid = tt > 0 ? 1.f : 0.f;
        float em_g  = fb[tt * T + lab_t];            // gather
        float tr_g  = trans_lds[lab_p * T + lab_t];  // LDS gather
        gold_part += em_g * mt + tr_g * (mp * mt) * valid;

        const float mreg = mt;  // lane i holds mask[base+i] for readlane

        const int i0 = (c == 0) ? 1 : 0;
        #pragma unroll 4
        for (int i = i0; i < T; ++i) {
            const int t = base + i;

            float em = em_n1;                 // emission for step t
            em_n1 = em_n2;
            int tn = t + 2; if (tn > S - 1) tn = S - 1;
            em_n2 = fb[tn * T + lane];        // prefetch t+2

            // normalizer: lane 1's alpha (tag 1 is never PAD-killed)
            float M  = __int_as_float(
                __builtin_amdgcn_readlane(__float_as_int(alpha), 1));
            float ea = __expf(alpha - M);

            ea_lds[t & 1][lane] = ea;
            asm volatile("s_waitcnt lgkmcnt(0)" ::: "memory");

            // s[j] = sum_i ea[i] * E[i][j], 16 uniform ds_read_b128 +
            // 32 v_pk_fma_f32
            const float4* ea4 = (const float4*)ea_lds[t & 1];
            f2 a01 = {0.f, 0.f}, a23 = {0.f, 0.f};
            #pragma unroll
            for (int k = 0; k < T / 4; ++k) {
                float4 v = ea4[k];
                a01 += f2{v.x, v.y} * etr2[2 * k + 0];
                a23 += f2{v.z, v.w} * etr2[2 * k + 1];
            }
            f2 accp = a01 + a23;
            float s = accp.x + accp.y;

            float m_t = __int_as_float(
                __builtin_amdgcn_readlane(__float_as_int(mreg), i));
            float val = M + __logf(s) + em;   // log(0) = -inf on PAD column
            val = fmaxf(val, -1e30f);         // finite so blend can't NaN
            alpha = val * m_t + alpha * (1.f - m_t);
        }
    }

    // ---- logZ = logsumexp over lanes (once; proper max reduce) ----
    float M2 = alpha;
    #pragma unroll
    for (int off = 32; off > 0; off >>= 1)
        M2 = fmaxf(M2, __shfl_xor(M2, off));
    float e2 = __expf(alpha - M2);
    #pragma unroll
    for (int off = 32; off > 0; off >>= 1)
        e2 += __shfl_xor(e2, off);
    float logZ = M2 + __logf(e2);

    // ---- gold: sum per-lane partials ----
    #pragma unroll
    for (int off = 32; off > 0; off >>= 1)
        gold_part += __shfl_xor(gold_part, off);

    if (lane == 0)
        ws[b] = logZ - gold_part;
}

// Deterministic final mean over B=128 per-batch results.
__global__ __launch_bounds__(128)
void crf_reduce(const float* __restrict__ ws, float* __restrict__ out)
{
    const int tid = threadIdx.x;
    float v = ws[tid];
    #pragma unroll
    for (int off = 32; off > 0; off >>= 1)
        v += __shfl_xor(v, off);

    __shared__ float partial[2];
    if ((tid & 63) == 0)
        partial[tid >> 6] = v;
    __syncthreads();
    if (tid == 0)
        out[0] = (partial[0] + partial[1]) * (1.0f / (float)B);
}

extern "C" void kernel_launch(void* const* d_in, const int* in_sizes, int n_in,
                              void* d_out, int out_size, void* d_ws, size_t ws_size,
                              hipStream_t stream)
{
    const float* features    = (const float*)d_in[0]; // (B,S,T) f32
    const int*   labels      = (const int*)  d_in[1]; // (B,S) int
    const float* mask        = (const float*)d_in[2]; // (B,S) f32
    const float* transitions = (const float*)d_in[3]; // (T,T) f32
    float* out = (float*)d_out;
    float* ws  = (float*)d_ws;   // needs B floats

    crf_fwd<<<dim3(B), dim3(64), 0, stream>>>(features, labels, mask, transitions, ws);
    crf_reduce<<<dim3(1), dim3(128), 0, stream>>>(ws, out);
}

// Round 3
// 145.263 us; speedup vs baseline: 2.1269x; 1.3051x over previous
//
#include <hip/hip_runtime.h>

#define B 128
#define S 512
#define T 64

typedef _Float16 h2 __attribute__((ext_vector_type(2)));

__device__ __forceinline__ float rdlane(float v, int l) {
    return __int_as_float(__builtin_amdgcn_readlane(__float_as_int(v), l));
}

// One wave (64 lanes) per batch element. Lane j owns tag j.
// Per-step LSE = exp-space matvec against E = exp(transitions), E held as
// packed-f16 column per lane (32 VGPR). ea broadcast through a 128-byte f16
// LDS buffer: 1 ds_write_b16 + 8 ds_read_b128 per step, consumed by
// v_dot2_f32_f16. launch_bounds(64,1) frees the full VGPR file so the read
// pipeline is never register-starved. No __syncthreads in the hot loop
// (single wave): explicit s_waitcnt lgkmcnt(0) orders LDS write->read;
// global prefetches stay in flight across steps.
__global__ __launch_bounds__(64, 1)
void crf_fwd(const float* __restrict__ features,
             const int*   __restrict__ labels,
             const float* __restrict__ mask,
             const float* __restrict__ transitions,
             float*       __restrict__ ws)
{
    __shared__ float trans_lds[T * T];
    __shared__ __align__(16) _Float16 ea_lds[2][T];

    const int lane = threadIdx.x;   // tag index j
    const int b    = blockIdx.x;    // batch element

    for (int i = 0; i < T; ++i)
        trans_lds[i * T + lane] = transitions[i * T + lane];
    __syncthreads();

    // etr[k] = (E[2k][lane], E[2k+1][lane]) packed f16; E = exp(W).
    h2 etr[T / 2];
    #pragma unroll
    for (int k = 0; k < T / 2; ++k) {
        etr[k].x = (_Float16)__expf(trans_lds[(2 * k + 0) * T + lane]);
        etr[k].y = (_Float16)__expf(trans_lds[(2 * k + 1) * T + lane]);
    }

    const float* fb = features + (size_t)b * S * T;
    const float* mb = mask + (size_t)b * S;
    const int*   lb = labels + (size_t)b * S;

    float alpha     = fb[lane];     // t = 0 emissions
    float gold_part = 0.f;
    float M         = 0.f;          // shared normalizer offset (alpha - M fed to exp)

    // emission prefetch pipeline, depth 3
    float em_n1 = fb[1 * T + lane];
    float em_n2 = fb[2 * T + lane];
    float em_n3 = fb[3 * T + lane];

    // chunk-0 label/mask prefetch (lane i handles gold for t = 64c + i)
    int   lab_c = lb[lane];
    int   lab_p = lb[lane > 0 ? lane - 1 : 0];
    float m_c   = mb[lane];
    float m_p   = mb[lane > 0 ? lane - 1 : 0];

    for (int c = 0; c < S / T; ++c) {
        const int base = c * T;
        const int tt   = base + lane;

        // capture current chunk's gold regs
        const int   glab  = lab_c;
        const int   glabp = lab_p;
        const float gmc   = m_c;
        const float gmp   = m_p;
        const float mreg  = m_c;          // lane i holds mask[base+i]

        // issue current-chunk gathers (consumed at chunk end)
        float em_g = fb[(size_t)tt * T + glab];
        float tr_g = trans_lds[glabp * T + glab];

        // prefetch next chunk's labels/mask (clamped for last chunk)
        {
            int tn  = tt + T;  if (tn > S - 1) tn = S - 1;
            int tnp = tn - 1;  if (tnp < 0) tnp = 0;
            lab_c = lb[tn];
            lab_p = lb[tnp];
            m_c   = mb[tn];
            m_p   = mb[tnp];
        }

        const int i0 = (c == 0) ? 1 : 0;
        #pragma unroll 4
        for (int i = i0; i < T; ++i) {
            const int t = base + i;

            float em = em_n1;                 // emission for step t
            em_n1 = em_n2;
            em_n2 = em_n3;
            int tn = t + 3; if (tn > S - 1) tn = S - 1;
            em_n3 = fb[tn * T + lane];        // prefetch t+3

            // ea = exp(alpha - M); broadcast via f16 LDS
            float ea = __expf(alpha - M);
            ea_lds[t & 1][lane] = (_Float16)ea;
            asm volatile("s_waitcnt lgkmcnt(0)" ::: "memory");

            // s[j] = sum_k ea[k] * E[k][j] : 8 uniform ds_read_b128 + 32 dot2
            const uint4* ep = (const uint4*)&ea_lds[t & 1][0];
            float a0 = 0.f, a1 = 0.f, a2 = 0.f, a3 = 0.f;
            #pragma unroll
            for (int q = 0; q < 8; ++q) {
                uint4 r = ep[q];
                a0 = __builtin_amdgcn_fdot2(__builtin_bit_cast(h2, r.x), etr[4 * q + 0], a0, false);
                a1 = __builtin_amdgcn_fdot2(__builtin_bit_cast(h2, r.y), etr[4 * q + 1], a1, false);
                a2 = __builtin_amdgcn_fdot2(__builtin_bit_cast(h2, r.z), etr[4 * q + 2], a2, false);
                a3 = __builtin_amdgcn_fdot2(__builtin_bit_cast(h2, r.w), etr[4 * q + 3], a3, false);
            }
            float s = (a0 + a1) + (a2 + a3);

            // scalar-side normalizer update, parallel to per-lane path
            float m_t = rdlane(mreg, i);
            float s1  = rdlane(s, 1);
            float em1 = rdlane(em, 1);
            float Mn  = M + __logf(s1) + em1; // alpha_new[1]

            // per-lane alpha update
            float val = M + __logf(s) + em;   // log(0) = -inf on PAD column
            val = fmaxf(val, -1e30f);         // keep finite so blend can't NaN
            alpha = val * m_t + alpha * (1.f - m_t);
            M     = (m_t > 0.5f) ? Mn : M;    // normalizer tracks alpha[1]
        }

        // gold partial for this chunk (loads long since landed)
        float valid = (tt > 0) ? 1.f : 0.f;
        gold_part += em_g * gmc + tr_g * (gmp * gmc) * valid;
    }

    // ---- logZ = logsumexp over lanes ----
    float M2 = alpha;
    #pragma unroll
    for (int off = 32; off > 0; off >>= 1)
        M2 = fmaxf(M2, __shfl_xor(M2, off));
    float e2 = __expf(alpha - M2);
    #pragma unroll
    for (int off = 32; off > 0; off >>= 1)
        e2 += __shfl_xor(e2, off);
    float logZ = M2 + __logf(e2);

    #pragma unroll
    for (int off = 32; off > 0; off >>= 1)
        gold_part += __shfl_xor(gold_part, off);

    if (lane == 0)
        ws[b] = logZ - gold_part;
}

// Deterministic final mean over B=128 per-batch results.
__global__ __launch_bounds__(128)
void crf_reduce(const float* __restrict__ ws, float* __restrict__ out)
{
    const int tid = threadIdx.x;
    float v = ws[tid];
    #pragma unroll
    for (int off = 32; off > 0; off >>= 1)
        v += __shfl_xor(v, off);

    __shared__ float partial[2];
    if ((tid & 63) == 0)
        partial[tid >> 6] = v;
    __syncthreads();
    if (tid == 0)
        out[0] = (partial[0] + partial[1]) * (1.0f / (float)B);
}

extern "C" void kernel_launch(void* const* d_in, const int* in_sizes, int n_in,
                              void* d_out, int out_size, void* d_ws, size_t ws_size,
                              hipStream_t stream)
{
    const float* features    = (const float*)d_in[0]; // (B,S,T) f32
    const int*   labels      = (const int*)  d_in[1]; // (B,S) int
    const float* mask        = (const float*)d_in[2]; // (B,S) f32
    const float* transitions = (const float*)d_in[3]; // (T,T) f32
    float* out = (float*)d_out;
    float* ws  = (float*)d_ws;   // needs B floats

    crf_fwd<<<dim3(B), dim3(64), 0, stream>>>(features, labels, mask, transitions, ws);
    crf_reduce<<<dim3(1), dim3(128), 0, stream>>>(ws, out);
}

// Round 6
// 88.804 us; speedup vs baseline: 3.4791x; 1.6358x over previous
//
#include <hip/hip_runtime.h>

#define B 128
#define S 512
#define T 64
#define G 16
#define CL 32   // steps per matrix chunk

typedef short bf16x8 __attribute__((ext_vector_type(8)));
typedef float f32x4 __attribute__((ext_vector_type(4)));
typedef _Float16 h2 __attribute__((ext_vector_type(2)));

__device__ __forceinline__ float rdlane(float v, int l) {
    return __int_as_float(__builtin_amdgcn_readlane(__float_as_int(v), l));
}
__device__ __forceinline__ unsigned cvtpk_bf16(float lo, float hi) {
    unsigned r;
    asm("v_cvt_pk_bf16_f32 %0, %1, %2" : "=v"(r) : "v"(lo), "v"(hi));
    return r;
}
// A/B fragment k-index for mfma_f32_16x16x32_bf16, SPLIT-HALF mapping:
// elements 0..3 -> k = 4*gq + e   (first 16x16x16 half)
// elements 4..7 -> k = 16 + 4*gq + (e-4)  (second half)
// Evidence: HW-verified tr_b16 read layout (m162) used 1:1 as MFMA B feed.
__device__ __forceinline__ int krow(int kt, int gq, int e) {
    return 32 * kt + ((e >> 2) << 4) + 4 * gq + (e & 3);
}

// ============================================================================
// Phase 1: one wave per (batch, chunk). Builds Z_g = prod_{t in chunk} (D_t*E^T)
// in bf16 (plus a power-of-2 int log-scale) via chained 64x64x64 MFMAs.
// Iteration: Z <- D_t * E^T * Z  (A = E^T static, B = Z).
// C-layout -> B-layout relayout via col-major padded LDS buffer.
// ============================================================================
__global__ __launch_bounds__(64, 1)
void crf_chunk(const float* __restrict__ features,
               const float* __restrict__ mask,
               const float* __restrict__ transitions,
               unsigned short* __restrict__ Zout,
               int* __restrict__ Kout)
{
    __shared__ unsigned short relay[T * 68];   // [col][row], padded rows

    const int lane = threadIdx.x;
    const int b  = blockIdx.x >> 4;
    const int g  = blockIdx.x & (G - 1);
    const int c  = lane & 15;
    const int gq = lane >> 4;

    // ---- A = E^T as mfma A-fragments (static): A[i][k] = exp(W[k][i]) ----
    // row i = c + 16*rt, k = krow(kt, gq, e)
    bf16x8 Af[4][2];
    #pragma unroll
    for (int rt = 0; rt < 4; ++rt)
      #pragma unroll
      for (int kt = 0; kt < 2; ++kt)
        #pragma unroll
        for (int w = 0; w < 4; ++w) {
            int e0 = 2 * w;
            int k0 = krow(kt, gq, e0);            // e0 even: k(e0+1) = k0+1
            float x0 = __expf(transitions[k0       * T + (c + 16*rt)]);
            float x1 = __expf(transitions[(k0 + 1) * T + (c + 16*rt)]);
            unsigned dw = cvtpk_bf16(x0, x1);
            Af[rt][kt][e0]     = (short)(dw & 0xFFFFu);
            Af[rt][kt][e0 + 1] = (short)(dw >> 16);
        }

    // ---- Z init = identity, in B-fragment layout: B[k][col] ----
    bf16x8 Bf[2][4];
    #pragma unroll
    for (int kt = 0; kt < 2; ++kt)
      #pragma unroll
      for (int ct = 0; ct < 4; ++ct)
        #pragma unroll
        for (int e = 0; e < 8; ++e)
            Bf[kt][ct][e] = (krow(kt, gq, e) == 16*ct + c) ? (short)0x3F80
                                                           : (short)0;

    const float* fb = features + (size_t)b * S * T;
    const int t0 = g * CL + 1;
    const int t1 = (g == G - 1) ? S : (t0 + CL);   // exclusive

    int kcur = 0, ktot = 0;

    // emission prefetch (rows 16*tr + 4*gq + 0..3 as float4)
    f32x4 emA[4];
    #pragma unroll
    for (int tr = 0; tr < 4; ++tr)
        emA[tr] = *(const f32x4*)(fb + t0 * T + 16*tr + 4*gq);
    float mA = mask[(size_t)b * S + t0];

    for (int t = t0; t < t1; ++t) {
        f32x4 em4[4];
        #pragma unroll
        for (int tr = 0; tr < 4; ++tr) em4[tr] = emA[tr];
        float m = mA;
        if (t + 1 < t1) {
            #pragma unroll
            for (int tr = 0; tr < 4; ++tr)
                emA[tr] = *(const f32x4*)(fb + (t + 1) * T + 16*tr + 4*gq);
            mA = mask[(size_t)b * S + t + 1];
        }
        if (m != 0.0f) {
            // C = E^T * Z  (f32 accum). C/D layout (HW-verified):
            // col = lane&15, row = 4*(lane>>4) + reg, per 16x16 tile.
            f32x4 C[4][4];
            #pragma unroll
            for (int tr = 0; tr < 4; ++tr)
              #pragma unroll
              for (int ct = 0; ct < 4; ++ct) {
                  f32x4 z = {0.f, 0.f, 0.f, 0.f};
                  z = __builtin_amdgcn_mfma_f32_16x16x32_bf16(Af[tr][0], Bf[0][ct], z, 0, 0, 0);
                  z = __builtin_amdgcn_mfma_f32_16x16x32_bf16(Af[tr][1], Bf[1][ct], z, 0, 0, 0);
                  C[tr][ct] = z;
              }
            // row-scale by exp(em_t[row]) * 2^-kcur, then clamp to finite
            float sc = __int_as_float((unsigned)(127 - kcur) << 23);
            #pragma unroll
            for (int tr = 0; tr < 4; ++tr) {
                f32x4 d4;
                #pragma unroll
                for (int r = 0; r < 4; ++r) d4[r] = __expf(em4[tr][r]) * sc;
                #pragma unroll
                for (int ct = 0; ct < 4; ++ct) {
                    C[tr][ct] *= d4;
                    #pragma unroll
                    for (int r = 0; r < 4; ++r)
                        C[tr][ct][r] = fminf(fmaxf(C[tr][ct][r], 0.f), 1e30f);
                }
            }
            // lagged rescale: measure max now, apply next step (exact pow2)
            float mx = 1e-30f;
            #pragma unroll
            for (int tr = 0; tr < 4; ++tr)
              #pragma unroll
              for (int ct = 0; ct < 4; ++ct)
                #pragma unroll
                for (int r = 0; r < 4; ++r) mx = fmaxf(mx, C[tr][ct][r]);
            #pragma unroll
            for (int o = 32; o > 0; o >>= 1)
                mx = fmaxf(mx, __shfl_xor(mx, o));
            ktot += kcur;  // scale applied this step
            kcur = (((__float_as_int(mx) >> 23) & 0xFF) - 127) + 8;
            kcur = kcur < -60 ? -60 : (kcur > 60 ? 60 : kcur);

            // cvt to bf16 + relayout C-layout -> B-layout via LDS.
            // write col-major: lane has 4 consecutive rows per tile (b64)
            #pragma unroll
            for (int tr = 0; tr < 4; ++tr)
              #pragma unroll
              for (int ct = 0; ct < 4; ++ct) {
                  unsigned d0 = cvtpk_bf16(C[tr][ct][0], C[tr][ct][1]);
                  unsigned d1 = cvtpk_bf16(C[tr][ct][2], C[tr][ct][3]);
                  int col = 16*ct + c, row0 = 16*tr + 4*gq;
                  uint2 w2; w2.x = d0; w2.y = d1;
                  *(uint2*)&relay[col * 68 + row0] = w2;
              }
            // write->read fence (wave-internal cross-lane LDS dataflow)
            asm volatile("s_waitcnt lgkmcnt(0)" ::: "memory");

            // read B-fragments: two b64 per frag, split-half k-mapping
            #pragma unroll
            for (int kt = 0; kt < 2; ++kt)
              #pragma unroll
              for (int ct = 0; ct < 4; ++ct) {
                  int col = 16*ct + c;
                  int rA = 32*kt + 4*gq;        // elements 0..3
                  int rB = 32*kt + 16 + 4*gq;   // elements 4..7
                  uint2 qa = *(const uint2*)&relay[col * 68 + rA];
                  uint2 qb = *(const uint2*)&relay[col * 68 + rB];
                  uint4 q; q.x = qa.x; q.y = qa.y; q.z = qb.x; q.w = qb.y;
                  Bf[kt][ct] = __builtin_bit_cast(bf16x8, q);
              }
            // read->next-write fence
            asm volatile("s_waitcnt lgkmcnt(0)" ::: "memory");
        }
    }

    // store Z row-major [64][64] bf16 + total scale (same mapping as read,
    // so Zout rows == relay rows == true Z rows regardless of mapping truth)
    unsigned short* zo = Zout + ((size_t)(b * G + g)) * 64 * 64;
    #pragma unroll
    for (int kt = 0; kt < 2; ++kt)
      #pragma unroll
      for (int ct = 0; ct < 4; ++ct)
        #pragma unroll
        for (int e = 0; e < 8; ++e)
            zo[krow(kt, gq, e) * 64 + 16*ct + c] = (unsigned short)Bf[kt][ct][e];
    if (lane == 0) Kout[b * G + g] = ktot;
}

// ============================================================================
// Phase 2: one wave per batch. v = exp(alpha - max), sequentially apply the
// 16 chunk matrices (v <- Z_g v), renormalizing by wave-max; plus gold score.
// ============================================================================
__global__ __launch_bounds__(64, 1)
void crf_apply(const float* __restrict__ features,
               const int*   __restrict__ labels,
               const float* __restrict__ mask,
               const float* __restrict__ transitions,
               const unsigned short* __restrict__ Zmat,
               const int*   __restrict__ Kscale,
               float*       __restrict__ res)
{
    __shared__ float trans_lds[T * T];
    __shared__ float bcast[2][T];
    const int lane = threadIdx.x;
    const int b = blockIdx.x;

    for (int i = 0; i < T; ++i)
        trans_lds[i * T + lane] = transitions[i * T + lane];
    __syncthreads();

    const float* fb = features + (size_t)b * S * T;
    const int*   lb = labels + (size_t)b * S;
    const float* mb = mask + (size_t)b * S;

    // ---- gold score (lane i handles t = 64*ch + i) ----
    float gold = 0.f;
    #pragma unroll
    for (int ch = 0; ch < S / T; ++ch) {
        int tt = ch * T + lane;
        int tm1 = tt > 0 ? tt - 1 : 0;
        int la = lb[tt], lp = lb[tm1];
        float mt = mb[tt], mp = mb[tm1];
        float em_g = fb[(size_t)tt * T + la];
        float tr_g = trans_lds[lp * T + la];
        gold += em_g * mt + ((tt > 0) ? tr_g * (mp * mt) : 0.f);
    }

    // ---- v init from alpha_0 = em_0, normalized by wave max ----
    float a0 = fb[lane];
    float A0 = a0;
    #pragma unroll
    for (int o = 32; o > 0; o >>= 1) A0 = fmaxf(A0, __shfl_xor(A0, o));
    float v = __expf(a0 - A0);
    float off = A0;

    // double-buffered Z-row loads (lane j holds row j)
    const unsigned short* zb = Zmat + ((size_t)b * G) * 64 * 64 + (size_t)lane * 64;
    uint4 cur[8], nxt[8];
    #pragma unroll
    for (int i = 0; i < 8; ++i) cur[i] = ((const uint4*)zb)[i];

    for (int g = 0; g < G; ++g) {
        if (g + 1 < G) {
            const uint4* zn = (const uint4*)(zb + (size_t)(g + 1) * 64 * 64);
            #pragma unroll
            for (int i = 0; i < 8; ++i) nxt[i] = zn[i];
        }
        const int buf = g & 1;
        bcast[buf][lane] = v;
        asm volatile("s_waitcnt lgkmcnt(0)" ::: "memory");
        f32x4 vb[16];
        #pragma unroll
        for (int q = 0; q < 16; ++q) vb[q] = ((const f32x4*)bcast[buf])[q];

        float acc = 0.f;
        #pragma unroll
        for (int i = 0; i < 8; ++i) {
            unsigned zz[4] = {cur[i].x, cur[i].y, cur[i].z, cur[i].w};
            #pragma unroll
            for (int d = 0; d < 4; ++d) {
                int k = i * 8 + d * 2;
                float f0 = __int_as_float(zz[d] << 16);
                float f1 = __int_as_float(zz[d] & 0xFFFF0000u);
                acc = fmaf(f0, vb[k >> 2][k & 3], acc);
                acc = fmaf(f1, vb[(k + 1) >> 2][(k + 1) & 3], acc);
            }
        }
        acc = fminf(fmaxf(acc, 0.f), 1e30f);
        // wave-max normalizer: v stays in [0,1], r strictly > 0
        float r = acc;
        #pragma unroll
        for (int o = 32; o > 0; o >>= 1) r = fmaxf(r, __shfl_xor(r, o));
        r = fmaxf(r, 1e-30f);
        v = acc / r;
        off += __logf(r) + (float)Kscale[b * G + g] * 0.69314718056f;
        #pragma unroll
        for (int i = 0; i < 8; ++i) cur[i] = nxt[i];
    }

    float sum = v;
    #pragma unroll
    for (int o = 32; o > 0; o >>= 1) sum += __shfl_xor(sum, o);
    float logZ = __logf(fmaxf(sum, 1e-30f)) + off;

    #pragma unroll
    for (int o = 32; o > 0; o >>= 1) gold += __shfl_xor(gold, o);

    if (lane == 0) res[b] = logZ - gold;
}

// ============================================================================
// Fallback: validated round-3 sequential kernel (used if ws too small)
// ============================================================================
__global__ __launch_bounds__(64, 1)
void crf_fwd_seq(const float* __restrict__ features,
                 const int*   __restrict__ labels,
                 const float* __restrict__ mask,
                 const float* __restrict__ transitions,
                 float*       __restrict__ ws)
{
    __shared__ float trans_lds[T * T];
    __shared__ __align__(16) _Float16 ea_lds[2][T];

    const int lane = threadIdx.x;
    const int b    = blockIdx.x;

    for (int i = 0; i < T; ++i)
        trans_lds[i * T + lane] = transitions[i * T + lane];
    __syncthreads();

    h2 etr[T / 2];
    #pragma unroll
    for (int k = 0; k < T / 2; ++k) {
        etr[k].x = (_Float16)__expf(trans_lds[(2 * k + 0) * T + lane]);
        etr[k].y = (_Float16)__expf(trans_lds[(2 * k + 1) * T + lane]);
    }

    const float* fb = features + (size_t)b * S * T;
    const float* mb = mask + (size_t)b * S;
    const int*   lb = labels + (size_t)b * S;

    float alpha = fb[lane];
    float gold_part = 0.f;
    float M = 0.f;

    float em_n1 = fb[1 * T + lane];
    float em_n2 = fb[2 * T + lane];
    float em_n3 = fb[3 * T + lane];

    int   lab_c = lb[lane];
    int   lab_p = lb[lane > 0 ? lane - 1 : 0];
    float m_c   = mb[lane];
    float m_p   = mb[lane > 0 ? lane - 1 : 0];

    for (int ch = 0; ch < S / T; ++ch) {
        const int base = ch * T;
        const int tt   = base + lane;

        const int   glab  = lab_c;
        const int   glabp = lab_p;
        const float gmc   = m_c;
        const float gmp   = m_p;
        const float mreg  = m_c;

        float em_g = fb[(size_t)tt * T + glab];
        float tr_g = trans_lds[glabp * T + glab];

        {
            int tn  = tt + T;  if (tn > S - 1) tn = S - 1;
            int tnp = tn - 1;  if (tnp < 0) tnp = 0;
            lab_c = lb[tn]; lab_p = lb[tnp];
            m_c   = mb[tn]; m_p   = mb[tnp];
        }

        const int i0 = (ch == 0) ? 1 : 0;
        #pragma unroll 4
        for (int i = i0; i < T; ++i) {
            const int t = base + i;
            float em = em_n1;
            em_n1 = em_n2; em_n2 = em_n3;
            int tn = t + 3; if (tn > S - 1) tn = S - 1;
            em_n3 = fb[tn * T + lane];

            float ea = __expf(alpha - M);
            ea_lds[t & 1][lane] = (_Float16)ea;
            asm volatile("s_waitcnt lgkmcnt(0)" ::: "memory");

            const uint4* ep = (const uint4*)&ea_lds[t & 1][0];
            float a0 = 0.f, a1 = 0.f, a2 = 0.f, a3 = 0.f;
            #pragma unroll
            for (int q = 0; q < 8; ++q) {
                uint4 r = ep[q];
                a0 = __builtin_amdgcn_fdot2(__builtin_bit_cast(h2, r.x), etr[4 * q + 0], a0, false);
                a1 = __builtin_amdgcn_fdot2(__builtin_bit_cast(h2, r.y), etr[4 * q + 1], a1, false);
                a2 = __builtin_amdgcn_fdot2(__builtin_bit_cast(h2, r.z), etr[4 * q + 2], a2, false);
                a3 = __builtin_amdgcn_fdot2(__builtin_bit_cast(h2, r.w), etr[4 * q + 3], a3, false);
            }
            float s = (a0 + a1) + (a2 + a3);

            float m_t = rdlane(mreg, i);
            float s1  = rdlane(s, 1);
            float em1 = rdlane(em, 1);
            float Mn  = M + __logf(s1) + em1;

            float val = M + __logf(s) + em;
            val = fmaxf(val, -1e30f);
            alpha = val * m_t + alpha * (1.f - m_t);
            M     = (m_t > 0.5f) ? Mn : M;
        }

        float valid = (tt > 0) ? 1.f : 0.f;
        gold_part += em_g * gmc + tr_g * (gmp * gmc) * valid;
    }

    float M2 = alpha;
    #pragma unroll
    for (int o = 32; o > 0; o >>= 1) M2 = fmaxf(M2, __shfl_xor(M2, o));
    float e2 = __expf(alpha - M2);
    #pragma unroll
    for (int o = 32; o > 0; o >>= 1) e2 += __shfl_xor(e2, o);
    float logZ = M2 + __logf(e2);

    #pragma unroll
    for (int o = 32; o > 0; o >>= 1) gold_part += __shfl_xor(gold_part, o);

    if (lane == 0) ws[b] = logZ - gold_part;
}

// Deterministic final mean over B=128 per-batch results.
__global__ __launch_bounds__(128)
void crf_reduce(const float* __restrict__ ws, float* __restrict__ out)
{
    const int tid = threadIdx.x;
    float v = ws[tid];
    #pragma unroll
    for (int o = 32; o > 0; o >>= 1) v += __shfl_xor(v, o);

    __shared__ float partial[2];
    if ((tid & 63) == 0) partial[tid >> 6] = v;
    __syncthreads();
    if (tid == 0) out[0] = (partial[0] + partial[1]) * (1.0f / (float)B);
}

extern "C" void kernel_launch(void* const* d_in, const int* in_sizes, int n_in,
                              void* d_out, int out_size, void* d_ws, size_t ws_size,
                              hipStream_t stream)
{
    const float* features    = (const float*)d_in[0]; // (B,S,T) f32
    const int*   labels      = (const int*)  d_in[1]; // (B,S) int
    const float* mask        = (const float*)d_in[2]; // (B,S) f32
    const float* transitions = (const float*)d_in[3]; // (T,T) f32
    float* out = (float*)d_out;

    const size_t zbytes = (size_t)B * G * 64 * 64 * sizeof(unsigned short); // 16 MB
    const size_t kbytes = (size_t)B * G * sizeof(int);
    const size_t need   = zbytes + kbytes + (size_t)B * sizeof(float);

    if (ws_size >= need) {
        unsigned short* Zmat = (unsigned short*)d_ws;
        int*   Ks  = (int*)((char*)d_ws + zbytes);
        float* res = (float*)((char*)d_ws + zbytes + kbytes);
        crf_chunk<<<dim3(B * G), dim3(64), 0, stream>>>(features, mask, transitions, Zmat, Ks);
        crf_apply<<<dim3(B), dim3(64), 0, stream>>>(features, labels, mask, transitions, Zmat, Ks, res);
        crf_reduce<<<dim3(1), dim3(128), 0, stream>>>(res, out);
    } else {
        float* res = (float*)d_ws;
        crf_fwd_seq<<<dim3(B), dim3(64), 0, stream>>>(features, labels, mask, transitions, res);
        crf_reduce<<<dim3(1), dim3(128), 0, stream>>>(res, out);
    }
}

// Round 7
// 75.740 us; speedup vs baseline: 4.0792x; 1.1725x over previous
//
#include <hip/hip_runtime.h>

#define B 128
#define S 512
#define T 64
#define G 16
#define CL 32   // steps per matrix chunk

typedef short bf16x8 __attribute__((ext_vector_type(8)));
typedef float f32x4 __attribute__((ext_vector_type(4)));
typedef _Float16 h2 __attribute__((ext_vector_type(2)));

__device__ __forceinline__ float rdlane(float v, int l) {
    return __int_as_float(__builtin_amdgcn_readlane(__float_as_int(v), l));
}
__device__ __forceinline__ unsigned cvtpk_bf16(float lo, float hi) {
    unsigned r;
    asm("v_cvt_pk_bf16_f32 %0, %1, %2" : "=v"(r) : "v"(lo), "v"(hi));
    return r;
}
// A/B fragment k-index for mfma_f32_16x16x32_bf16, SPLIT-HALF mapping
// (validated round 6, absmax=0): e=0..3 -> k=4*gq+e ; e=4..7 -> k=16+4*gq+(e-4)
__device__ __forceinline__ int krow(int kt, int gq, int e) {
    return 32 * kt + ((e >> 2) << 4) + 4 * gq + (e & 3);
}

// ============================================================================
// Phase 1: one wave per (batch, chunk). Builds Z_g = prod_{t in chunk} (D_t*E^T)
// in bf16 (plus a power-of-2 int log-scale) via chained 64x64x64 MFMAs.
// KEY (round 7): the C-layout -> B-layout relayout is LANE-LOCAL:
//   C tile tr, lane(c,gq) holds rows 16*tr+4*gq+{0..3}, col 16*ct+c;
//   B frag kt needs k-rows 32*kt+{0,16}+4*gq+{0..3} = C tiles 2kt, 2kt+1.
// So Bf is built with cvt_pk only — no LDS, no fences in the hot loop.
// ============================================================================
__global__ __launch_bounds__(64, 1)
void crf_chunk(const float* __restrict__ features,
               const float* __restrict__ mask,
               const float* __restrict__ transitions,
               unsigned short* __restrict__ Zout,
               int* __restrict__ Kout)
{
    __shared__ unsigned short relay[T * 68];   // [col][row], used ONCE at end

    const int lane = threadIdx.x;
    const int b  = blockIdx.x >> 4;
    const int g  = blockIdx.x & (G - 1);
    const int c  = lane & 15;
    const int gq = lane >> 4;

    // ---- A = E^T as mfma A-fragments (static): A[i][k] = exp(W[k][i]) ----
    bf16x8 Af[4][2];
    #pragma unroll
    for (int rt = 0; rt < 4; ++rt)
      #pragma unroll
      for (int kt = 0; kt < 2; ++kt)
        #pragma unroll
        for (int w = 0; w < 4; ++w) {
            int e0 = 2 * w;
            int k0 = krow(kt, gq, e0);            // e0 even: k(e0+1) = k0+1
            float x0 = __expf(transitions[k0       * T + (c + 16*rt)]);
            float x1 = __expf(transitions[(k0 + 1) * T + (c + 16*rt)]);
            unsigned dw = cvtpk_bf16(x0, x1);
            Af[rt][kt][e0]     = (short)(dw & 0xFFFFu);
            Af[rt][kt][e0 + 1] = (short)(dw >> 16);
        }

    // ---- Z init = identity, in B-fragment layout: B[k][col] ----
    bf16x8 Bf[2][4];
    #pragma unroll
    for (int kt = 0; kt < 2; ++kt)
      #pragma unroll
      for (int ct = 0; ct < 4; ++ct)
        #pragma unroll
        for (int e = 0; e < 8; ++e)
            Bf[kt][ct][e] = (krow(kt, gq, e) == 16*ct + c) ? (short)0x3F80
                                                           : (short)0;

    const float* fb = features + (size_t)b * S * T;
    const int t0 = g * CL + 1;
    const int t1 = (g == G - 1) ? S : (t0 + CL);   // exclusive

    int kcur = 0, ktot = 0;

    // emission prefetch (rows 16*tr + 4*gq + 0..3 as float4)
    f32x4 emA[4];
    #pragma unroll
    for (int tr = 0; tr < 4; ++tr)
        emA[tr] = *(const f32x4*)(fb + t0 * T + 16*tr + 4*gq);
    float mA = mask[(size_t)b * S + t0];

    for (int t = t0; t < t1; ++t) {
        f32x4 em4[4];
        #pragma unroll
        for (int tr = 0; tr < 4; ++tr) em4[tr] = emA[tr];
        float m = mA;
        if (t + 1 < t1) {
            #pragma unroll
            for (int tr = 0; tr < 4; ++tr)
                emA[tr] = *(const f32x4*)(fb + (t + 1) * T + 16*tr + 4*gq);
            mA = mask[(size_t)b * S + t + 1];
        }
        if (m != 0.0f) {
            // C = E^T * Z  (f32 accum); C/D: col=lane&15, row=4*(lane>>4)+reg
            f32x4 C[4][4];
            #pragma unroll
            for (int tr = 0; tr < 4; ++tr)
              #pragma unroll
              for (int ct = 0; ct < 4; ++ct) {
                  f32x4 z = {0.f, 0.f, 0.f, 0.f};
                  z = __builtin_amdgcn_mfma_f32_16x16x32_bf16(Af[tr][0], Bf[0][ct], z, 0, 0, 0);
                  z = __builtin_amdgcn_mfma_f32_16x16x32_bf16(Af[tr][1], Bf[1][ct], z, 0, 0, 0);
                  C[tr][ct] = z;
              }
            // row-scale by exp(em_t[row]) * 2^-kcur (lagged exact pow2)
            float sc = __int_as_float((unsigned)(127 - kcur) << 23);
            #pragma unroll
            for (int tr = 0; tr < 4; ++tr) {
                f32x4 d4;
                #pragma unroll
                for (int r = 0; r < 4; ++r) d4[r] = __expf(em4[tr][r]) * sc;
                #pragma unroll
                for (int ct = 0; ct < 4; ++ct) C[tr][ct] *= d4;
            }
            // lagged rescale bookkeeping (off critical path: applied next t)
            float mx = 1e-30f;
            #pragma unroll
            for (int tr = 0; tr < 4; ++tr)
              #pragma unroll
              for (int ct = 0; ct < 4; ++ct) {
                  float m01 = fmaxf(C[tr][ct][0], C[tr][ct][1]);
                  float m23 = fmaxf(C[tr][ct][2], C[tr][ct][3]);
                  mx = fmaxf(mx, fmaxf(m01, m23));
              }
            #pragma unroll
            for (int o = 32; o > 0; o >>= 1)
                mx = fmaxf(mx, __shfl_xor(mx, o));
            ktot += kcur;  // scale applied this step
            kcur = (((__float_as_int(mx) >> 23) & 0xFF) - 127) + 8;
            kcur = kcur < -60 ? -60 : (kcur > 60 ? 60 : kcur);

            // LANE-LOCAL repack: Bf[kt][ct] <- C[2kt][ct] , C[2kt+1][ct]
            #pragma unroll
            for (int kt = 0; kt < 2; ++kt)
              #pragma unroll
              for (int ct = 0; ct < 4; ++ct) {
                  uint4 q;
                  q.x = cvtpk_bf16(C[2*kt  ][ct][0], C[2*kt  ][ct][1]);
                  q.y = cvtpk_bf16(C[2*kt  ][ct][2], C[2*kt  ][ct][3]);
                  q.z = cvtpk_bf16(C[2*kt+1][ct][0], C[2*kt+1][ct][1]);
                  q.w = cvtpk_bf16(C[2*kt+1][ct][2], C[2*kt+1][ct][3]);
                  Bf[kt][ct] = __builtin_bit_cast(bf16x8, q);
              }
        }
    }

    // ---- ONE-TIME relayout to row-major Zout via LDS ----
    // write col-major: frag elements 0..3 are 4 consecutive rows (b64)
    #pragma unroll
    for (int kt = 0; kt < 2; ++kt)
      #pragma unroll
      for (int ct = 0; ct < 4; ++ct) {
          uint4 q = __builtin_bit_cast(uint4, Bf[kt][ct]);
          int col = 16*ct + c;
          uint2 wa; wa.x = q.x; wa.y = q.y;     // rows 32kt+4gq+0..3
          uint2 wb; wb.x = q.z; wb.y = q.w;     // rows 32kt+16+4gq+0..3
          *(uint2*)&relay[col * 68 + 32*kt      + 4*gq] = wa;
          *(uint2*)&relay[col * 68 + 32*kt + 16 + 4*gq] = wb;
      }
    asm volatile("s_waitcnt lgkmcnt(0)" ::: "memory");

    // each lane reads its row (row = lane) across cols, stores row-major
    unsigned short* zo = Zout + ((size_t)(b * G + g)) * 64 * 64;
    #pragma unroll
    for (int q8 = 0; q8 < 8; ++q8) {
        unsigned dw[4];
        #pragma unroll
        for (int d = 0; d < 4; ++d) {
            unsigned lo = relay[(8*q8 + 2*d    ) * 68 + lane];
            unsigned hi = relay[(8*q8 + 2*d + 1) * 68 + lane];
            dw[d] = lo | (hi << 16);
        }
        uint4 w; w.x = dw[0]; w.y = dw[1]; w.z = dw[2]; w.w = dw[3];
        *(uint4*)(zo + (size_t)lane * 64 + 8*q8) = w;
    }
    if (lane == 0) Kout[b * G + g] = ktot;
}

// ============================================================================
// Phase 2: one wave per batch. v = exp(alpha - max), sequentially apply the
// 16 chunk matrices (v <- Z_g v), renormalizing by wave-max; plus gold score.
// ============================================================================
__global__ __launch_bounds__(64, 1)
void crf_apply(const float* __restrict__ features,
               const int*   __restrict__ labels,
               const float* __restrict__ mask,
               const float* __restrict__ transitions,
               const unsigned short* __restrict__ Zmat,
               const int*   __restrict__ Kscale,
               float*       __restrict__ res)
{
    __shared__ float trans_lds[T * T];
    __shared__ float bcast[2][T];
    const int lane = threadIdx.x;
    const int b = blockIdx.x;

    for (int i = 0; i < T; ++i)
        trans_lds[i * T + lane] = transitions[i * T + lane];
    __syncthreads();

    const float* fb = features + (size_t)b * S * T;
    const int*   lb = labels + (size_t)b * S;
    const float* mb = mask + (size_t)b * S;

    // ---- gold score (lane i handles t = 64*ch + i) ----
    float gold = 0.f;
    #pragma unroll
    for (int ch = 0; ch < S / T; ++ch) {
        int tt = ch * T + lane;
        int tm1 = tt > 0 ? tt - 1 : 0;
        int la = lb[tt], lp = lb[tm1];
        float mt = mb[tt], mp = mb[tm1];
        float em_g = fb[(size_t)tt * T + la];
        float tr_g = trans_lds[lp * T + la];
        gold += em_g * mt + ((tt > 0) ? tr_g * (mp * mt) : 0.f);
    }

    // ---- v init from alpha_0 = em_0, normalized by wave max ----
    float a0 = fb[lane];
    float A0 = a0;
    #pragma unroll
    for (int o = 32; o > 0; o >>= 1) A0 = fmaxf(A0, __shfl_xor(A0, o));
    float v = __expf(a0 - A0);
    float off = A0;

    // double-buffered Z-row loads (lane j holds row j)
    const unsigned short* zb = Zmat + ((size_t)b * G) * 64 * 64 + (size_t)lane * 64;
    uint4 cur[8], nxt[8];
    #pragma unroll
    for (int i = 0; i < 8; ++i) cur[i] = ((const uint4*)zb)[i];

    for (int g = 0; g < G; ++g) {
        if (g + 1 < G) {
            const uint4* zn = (const uint4*)(zb + (size_t)(g + 1) * 64 * 64);
            #pragma unroll
            for (int i = 0; i < 8; ++i) nxt[i] = zn[i];
        }
        const int buf = g & 1;
        bcast[buf][lane] = v;
        asm volatile("s_waitcnt lgkmcnt(0)" ::: "memory");
        f32x4 vb[16];
        #pragma unroll
        for (int q = 0; q < 16; ++q) vb[q] = ((const f32x4*)bcast[buf])[q];

        float acc = 0.f;
        #pragma unroll
        for (int i = 0; i < 8; ++i) {
            unsigned zz[4] = {cur[i].x, cur[i].y, cur[i].z, cur[i].w};
            #pragma unroll
            for (int d = 0; d < 4; ++d) {
                int k = i * 8 + d * 2;
                float f0 = __int_as_float(zz[d] << 16);
                float f1 = __int_as_float(zz[d] & 0xFFFF0000u);
                acc = fmaf(f0, vb[k >> 2][k & 3], acc);
                acc = fmaf(f1, vb[(k + 1) >> 2][(k + 1) & 3], acc);
            }
        }
        acc = fminf(fmaxf(acc, 0.f), 1e30f);
        // wave-max normalizer: v stays in [0,1], r strictly > 0
        float r = acc;
        #pragma unroll
        for (int o = 32; o > 0; o >>= 1) r = fmaxf(r, __shfl_xor(r, o));
        r = fmaxf(r, 1e-30f);
        v = acc / r;
        off += __logf(r) + (float)Kscale[b * G + g] * 0.69314718056f;
        #pragma unroll
        for (int i = 0; i < 8; ++i) cur[i] = nxt[i];
    }

    float sum = v;
    #pragma unroll
    for (int o = 32; o > 0; o >>= 1) sum += __shfl_xor(sum, o);
    float logZ = __logf(fmaxf(sum, 1e-30f)) + off;

    #pragma unroll
    for (int o = 32; o > 0; o >>= 1) gold += __shfl_xor(gold, o);

    if (lane == 0) res[b] = logZ - gold;
}

// ============================================================================
// Fallback: validated round-3 sequential kernel (used if ws too small)
// ============================================================================
__global__ __launch_bounds__(64, 1)
void crf_fwd_seq(const float* __restrict__ features,
                 const int*   __restrict__ labels,
                 const float* __restrict__ mask,
                 const float* __restrict__ transitions,
                 float*       __restrict__ ws)
{
    __shared__ float trans_lds[T * T];
    __shared__ __align__(16) _Float16 ea_lds[2][T];

    const int lane = threadIdx.x;
    const int b    = blockIdx.x;

    for (int i = 0; i < T; ++i)
        trans_lds[i * T + lane] = transitions[i * T + lane];
    __syncthreads();

    h2 etr[T / 2];
    #pragma unroll
    for (int k = 0; k < T / 2; ++k) {
        etr[k].x = (_Float16)__expf(trans_lds[(2 * k + 0) * T + lane]);
        etr[k].y = (_Float16)__expf(trans_lds[(2 * k + 1) * T + lane]);
    }

    const float* fb = features + (size_t)b * S * T;
    const float* mb = mask + (size_t)b * S;
    const int*   lb = labels + (size_t)b * S;

    float alpha = fb[lane];
    float gold_part = 0.f;
    float M = 0.f;

    float em_n1 = fb[1 * T + lane];
    float em_n2 = fb[2 * T + lane];
    float em_n3 = fb[3 * T + lane];

    int   lab_c = lb[lane];
    int   lab_p = lb[lane > 0 ? lane - 1 : 0];
    float m_c   = mb[lane];
    float m_p   = mb[lane > 0 ? lane - 1 : 0];

    for (int ch = 0; ch < S / T; ++ch) {
        const int base = ch * T;
        const int tt   = base + lane;

        const int   glab  = lab_c;
        const int   glabp = lab_p;
        const float gmc   = m_c;
        const float gmp   = m_p;
        const float mreg  = m_c;

        float em_g = fb[(size_t)tt * T + glab];
        float tr_g = trans_lds[glabp * T + glab];

        {
            int tn  = tt + T;  if (tn > S - 1) tn = S - 1;
            int tnp = tn - 1;  if (tnp < 0) tnp = 0;
            lab_c = lb[tn]; lab_p = lb[tnp];
            m_c   = mb[tn]; m_p   = mb[tnp];
        }

        const int i0 = (ch == 0) ? 1 : 0;
        #pragma unroll 4
        for (int i = i0; i < T; ++i) {
            const int t = base + i;
            float em = em_n1;
            em_n1 = em_n2; em_n2 = em_n3;
            int tn = t + 3; if (tn > S - 1) tn = S - 1;
            em_n3 = fb[tn * T + lane];

            float ea = __expf(alpha - M);
            ea_lds[t & 1][lane] = (_Float16)ea;
            asm volatile("s_waitcnt lgkmcnt(0)" ::: "memory");

            const uint4* ep = (const uint4*)&ea_lds[t & 1][0];
            float a0 = 0.f, a1 = 0.f, a2 = 0.f, a3 = 0.f;
            #pragma unroll
            for (int q = 0; q < 8; ++q) {
                uint4 r = ep[q];
                a0 = __builtin_amdgcn_fdot2(__builtin_bit_cast(h2, r.x), etr[4 * q + 0], a0, false);
                a1 = __builtin_amdgcn_fdot2(__builtin_bit_cast(h2, r.y), etr[4 * q + 1], a1, false);
                a2 = __builtin_amdgcn_fdot2(__builtin_bit_cast(h2, r.z), etr[4 * q + 2], a2, false);
                a3 = __builtin_amdgcn_fdot2(__builtin_bit_cast(h2, r.w), etr[4 * q + 3], a3, false);
            }
            float s = (a0 + a1) + (a2 + a3);

            float m_t = rdlane(mreg, i);
            float s1  = rdlane(s, 1);
            float em1 = rdlane(em, 1);
            float Mn  = M + __logf(s1) + em1;

            float val = M + __logf(s) + em;
            val = fmaxf(val, -1e30f);
            alpha = val * m_t + alpha * (1.f - m_t);
            M     = (m_t > 0.5f) ? Mn : M;
        }

        float valid = (tt > 0) ? 1.f : 0.f;
        gold_part += em_g * gmc + tr_g * (gmp * gmc) * valid;
    }

    float M2 = alpha;
    #pragma unroll
    for (int o = 32; o > 0; o >>= 1) M2 = fmaxf(M2, __shfl_xor(M2, o));
    float e2 = __expf(alpha - M2);
    #pragma unroll
    for (int o = 32; o > 0; o >>= 1) e2 += __shfl_xor(e2, o);
    float logZ = M2 + __logf(e2);

    #pragma unroll
    for (int o = 32; o > 0; o >>= 1) gold_part += __shfl_xor(gold_part, o);

    if (lane == 0) ws[b] = logZ - gold_part;
}

// Deterministic final mean over B=128 per-batch results.
__global__ __launch_bounds__(128)
void crf_reduce(const float* __restrict__ ws, float* __restrict__ out)
{
    const int tid = threadIdx.x;
    float v = ws[tid];
    #pragma unroll
    for (int o = 32; o > 0; o >>= 1) v += __shfl_xor(v, o);

    __shared__ float partial[2];
    if ((tid & 63) == 0) partial[tid >> 6] = v;
    __syncthreads();
    if (tid == 0) out[0] = (partial[0] + partial[1]) * (1.0f / (float)B);
}

extern "C" void kernel_launch(void* const* d_in, const int* in_sizes, int n_in,
                              void* d_out, int out_size, void* d_ws, size_t ws_size,
                              hipStream_t stream)
{
    const float* features    = (const float*)d_in[0]; // (B,S,T) f32
    const int*   labels      = (const int*)  d_in[1]; // (B,S) int
    const float* mask        = (const float*)d_in[2]; // (B,S) f32
    const float* transitions = (const float*)d_in[3]; // (T,T) f32
    float* out = (float*)d_out;

    const size_t zbytes = (size_t)B * G * 64 * 64 * sizeof(unsigned short); // 16 MB
    const size_t kbytes = (size_t)B * G * sizeof(int);
    const size_t need   = zbytes + kbytes + (size_t)B * sizeof(float);

    if (ws_size >= need) {
        unsigned short* Zmat = (unsigned short*)d_ws;
        int*   Ks  = (int*)((char*)d_ws + zbytes);
        float* res = (float*)((char*)d_ws + zbytes + kbytes);
        crf_chunk<<<dim3(B * G), dim3(64), 0, stream>>>(features, mask, transitions, Zmat, Ks);
        crf_apply<<<dim3(B), dim3(64), 0, stream>>>(features, labels, mask, transitions, Zmat, Ks, res);
        crf_reduce<<<dim3(1), dim3(128), 0, stream>>>(res, out);
    } else {
        float* res = (float*)d_ws;
        crf_fwd_seq<<<dim3(B), dim3(64), 0, stream>>>(features, labels, mask, transitions, res);
        crf_reduce<<<dim3(1), dim3(128), 0, stream>>>(res, out);
    }
}

// Round 9
// 68.204 us; speedup vs baseline: 4.5299x; 1.1105x over previous
//
#include <hip/hip_runtime.h>

#define B 128
#define S 512
#define T 64
#define G 16
#define CL 32   // steps per matrix chunk

typedef short bf16x8 __attribute__((ext_vector_type(8)));
typedef float f32x4 __attribute__((ext_vector_type(4)));
typedef _Float16 h2 __attribute__((ext_vector_type(2)));
typedef _Float16 h8 __attribute__((ext_vector_type(8)));

__device__ __forceinline__ float rdlane(float v, int l) {
    return __int_as_float(__builtin_amdgcn_readlane(__float_as_int(v), l));
}
__device__ __forceinline__ unsigned cvtpk_bf16(float lo, float hi) {
    unsigned r;
    asm("v_cvt_pk_bf16_f32 %0, %1, %2" : "=v"(r) : "v"(lo), "v"(hi));
    return r;
}
// packed f32->f16 (RTZ), returns the two f16 in one dword
__device__ __forceinline__ unsigned cvt_pkrtz_u(float lo, float hi) {
    unsigned r;
    asm("v_cvt_pkrtz_f16_f32 %0, %1, %2" : "=v"(r) : "v"(lo), "v"(hi));
    return r;
}
__device__ __forceinline__ float fast_exp2(float x) {
    float r;
    asm("v_exp_f32 %0, %1" : "=v"(r) : "v"(x));
    return r;
}
// A/B fragment k-index for mfma_f32_16x16x32_{bf16,f16}, SPLIT-HALF mapping
// (validated round 6, absmax=0): e=0..3 -> k=4*gq+e ; e=4..7 -> k=16+4*gq+(e-4)
__device__ __forceinline__ int krow(int kt, int gq, int e) {
    return 32 * kt + ((e >> 2) << 4) + 4 * gq + (e & 3);
}

// ============================================================================
// Phase 1: one wave per (batch, chunk). Builds Z_g = prod_t (D_t*E^T) in f16
// (plus power-of-2 int log-scale) via chained 64x64x64 f16 MFMAs.
// Diagonal folded into the A operand (row i = lane.c + 16*rt is
// per-fragment-uniform): A'_t = (d .* E^T) built with v_pk_mul_f16 and
// only 4 v_exp per step; MFMA output is final (no C-side scaling).
// Repack C->B stays lane-local (cvt_pkrtz only).
// ============================================================================
__global__ __launch_bounds__(64, 1)
void crf_chunk(const float* __restrict__ features,
               const float* __restrict__ mask,
               const float* __restrict__ transitions,
               unsigned short* __restrict__ Zout,
               int* __restrict__ Kout)
{
    __shared__ unsigned short relay[T * 68];   // [col][row], used ONCE at end

    const int lane = threadIdx.x;
    const int b  = blockIdx.x >> 4;
    const int g  = blockIdx.x & (G - 1);
    const int c  = lane & 15;
    const int gq = lane >> 4;

    // ---- static E^T fragments in f16: Ef[rt][kt][e] = exp(W[k][i]),
    //      i = c + 16*rt, k = krow(kt,gq,e). Track global E max for clamp.
    h8 Ef[4][2];
    float emaxv = 1e-10f;
    #pragma unroll
    for (int rt = 0; rt < 4; ++rt)
      #pragma unroll
      for (int kt = 0; kt < 2; ++kt)
        #pragma unroll
        for (int e = 0; e < 8; ++e) {
            int k = krow(kt, gq, e);
            float x = __expf(transitions[k * T + (c + 16*rt)]);
            emaxv = fmaxf(emaxv, x);
            Ef[rt][kt][e] = (_Float16)x;
        }
    #pragma unroll
    for (int o = 32; o > 0; o >>= 1)
        emaxv = fmaxf(emaxv, __shfl_xor(emaxv, o));
    const float dmax = 60000.0f / emaxv;   // keeps A' inside f16 range

    // ---- Z init = identity, in B-fragment layout: B[k][col] ----
    h8 Bf[2][4];
    #pragma unroll
    for (int kt = 0; kt < 2; ++kt)
      #pragma unroll
      for (int ct = 0; ct < 4; ++ct)
        #pragma unroll
        for (int e = 0; e < 8; ++e)
            Bf[kt][ct][e] = (krow(kt, gq, e) == 16*ct + c) ? (_Float16)1.0f
                                                           : (_Float16)0.0f;

    const float* fb   = features + (size_t)b * S * T;
    const float* colp = fb + c;            // this lane's A-row column base
    const int t0 = g * CL + 1;
    const int t1 = (g == G - 1) ? S : (t0 + CL);   // exclusive

    int kcur = 0, ktot = 0;

    // emission prefetch: em[t, c+16*rt] (A-row distribution), depth 1
    float emN[4];
    #pragma unroll
    for (int rt = 0; rt < 4; ++rt) emN[rt] = colp[t0 * T + 16*rt];
    float mA = mask[(size_t)b * S + t0];

    for (int t = t0; t < t1; ++t) {
        float emc[4];
        #pragma unroll
        for (int rt = 0; rt < 4; ++rt) emc[rt] = emN[rt];
        float m = mA;
        if (t + 1 < t1) {
            #pragma unroll
            for (int rt = 0; rt < 4; ++rt)
                emN[rt] = colp[(t + 1) * T + 16*rt];
            mA = mask[(size_t)b * S + t + 1];
        }
        if (m != 0.0f) {
            // d_rt = exp(em) * 2^-kcur = exp2(em*log2e - kcur), clamped
            const float kcf = (float)kcur;
            h8 Ap[4][2];
            #pragma unroll
            for (int rt = 0; rt < 4; ++rt) {
                float d = fast_exp2(fmaf(emc[rt], 1.44269504f, -kcf));
                d = fminf(d, dmax);
                unsigned w = cvt_pkrtz_u(d, d);
                uint4 qs; qs.x = w; qs.y = w; qs.z = w; qs.w = w;
                h8 ds = __builtin_bit_cast(h8, qs);
                Ap[rt][0] = Ef[rt][0] * ds;    // v_pk_mul_f16
                Ap[rt][1] = Ef[rt][1] * ds;
            }

            // C = A' * Z (f32 accum) — already fully scaled
            f32x4 C[4][4];
            #pragma unroll
            for (int tr = 0; tr < 4; ++tr)
              #pragma unroll
              for (int ct = 0; ct < 4; ++ct) {
                  f32x4 z = {0.f, 0.f, 0.f, 0.f};
                  z = __builtin_amdgcn_mfma_f32_16x16x32_f16(Ap[tr][0], Bf[0][ct], z, 0, 0, 0);
                  z = __builtin_amdgcn_mfma_f32_16x16x32_f16(Ap[tr][1], Bf[1][ct], z, 0, 0, 0);
                  C[tr][ct] = z;
              }

            // lagged rescale bookkeeping (applied next step via kcur)
            float mx = 1e-30f;
            #pragma unroll
            for (int tr = 0; tr < 4; ++tr)
              #pragma unroll
              for (int ct = 0; ct < 4; ++ct) {
                  float m01 = fmaxf(C[tr][ct][0], C[tr][ct][1]);
                  float m23 = fmaxf(C[tr][ct][2], C[tr][ct][3]);
                  mx = fmaxf(mx, fmaxf(m01, m23));
              }
            #pragma unroll
            for (int o = 32; o > 0; o >>= 1)
                mx = fmaxf(mx, __shfl_xor(mx, o));
            ktot += kcur;
            kcur = (((__float_as_int(mx) >> 23) & 0xFF) - 127) + 8;
            kcur = kcur < -60 ? -60 : (kcur > 60 ? 60 : kcur);

            // LANE-LOCAL repack: Bf[kt][ct] <- C[2kt][ct], C[2kt+1][ct] (f16)
            #pragma unroll
            for (int kt = 0; kt < 2; ++kt)
              #pragma unroll
              for (int ct = 0; ct < 4; ++ct) {
                  uint4 q;
                  q.x = cvt_pkrtz_u(C[2*kt  ][ct][0], C[2*kt  ][ct][1]);
                  q.y = cvt_pkrtz_u(C[2*kt  ][ct][2], C[2*kt  ][ct][3]);
                  q.z = cvt_pkrtz_u(C[2*kt+1][ct][0], C[2*kt+1][ct][1]);
                  q.w = cvt_pkrtz_u(C[2*kt+1][ct][2], C[2*kt+1][ct][3]);
                  Bf[kt][ct] = __builtin_bit_cast(h8, q);
              }
        }
    }

    // ---- ONE-TIME: convert f16 frags to bf16 dwords, relayout via LDS ----
    #pragma unroll
    for (int kt = 0; kt < 2; ++kt)
      #pragma unroll
      for (int ct = 0; ct < 4; ++ct) {
          int col = 16*ct + c;
          unsigned dw[4];
          #pragma unroll
          for (int p = 0; p < 4; ++p)
              dw[p] = cvtpk_bf16((float)Bf[kt][ct][2*p], (float)Bf[kt][ct][2*p+1]);
          uint2 wa; wa.x = dw[0]; wa.y = dw[1];   // rows 32kt+4gq+0..3
          uint2 wb; wb.x = dw[2]; wb.y = dw[3];   // rows 32kt+16+4gq+0..3
          *(uint2*)&relay[col * 68 + 32*kt      + 4*gq] = wa;
          *(uint2*)&relay[col * 68 + 32*kt + 16 + 4*gq] = wb;
      }
    asm volatile("s_waitcnt lgkmcnt(0)" ::: "memory");

    // each lane reads its row (row = lane) across cols, stores row-major
    unsigned short* zo = Zout + ((size_t)(b * G + g)) * 64 * 64;
    #pragma unroll
    for (int q8 = 0; q8 < 8; ++q8) {
        unsigned dw[4];
        #pragma unroll
        for (int d = 0; d < 4; ++d) {
            unsigned lo = relay[(8*q8 + 2*d    ) * 68 + lane];
            unsigned hi = relay[(8*q8 + 2*d + 1) * 68 + lane];
            dw[d] = lo | (hi << 16);
        }
        uint4 w; w.x = dw[0]; w.y = dw[1]; w.z = dw[2]; w.w = dw[3];
        *(uint4*)(zo + (size_t)lane * 64 + 8*q8) = w;
    }
    if (lane == 0) Kout[b * G + g] = ktot;
}

// ============================================================================
// Phase 2: one wave per batch. v = exp(alpha - max), sequentially apply the
// 16 chunk matrices (v <- Z_g v), renormalizing by wave-max; plus gold score.
// ============================================================================
__global__ __launch_bounds__(64, 1)
void crf_apply(const float* __restrict__ features,
               const int*   __restrict__ labels,
               const float* __restrict__ mask,
               const float* __restrict__ transitions,
               const unsigned short* __restrict__ Zmat,
               const int*   __restrict__ Kscale,
               float*       __restrict__ res)
{
    __shared__ float trans_lds[T * T];
    __shared__ float bcast[2][T];
    const int lane = threadIdx.x;
    const int b = blockIdx.x;

    for (int i = 0; i < T; ++i)
        trans_lds[i * T + lane] = transitions[i * T + lane];
    __syncthreads();

    const float* fb = features + (size_t)b * S * T;
    const int*   lb = labels + (size_t)b * S;
    const float* mb = mask + (size_t)b * S;

    // ---- gold score (lane i handles t = 64*ch + i) ----
    float gold = 0.f;
    #pragma unroll
    for (int ch = 0; ch < S / T; ++ch) {
        int tt = ch * T + lane;
        int tm1 = tt > 0 ? tt - 1 : 0;
        int la = lb[tt], lp = lb[tm1];
        float mt = mb[tt], mp = mb[tm1];
        float em_g = fb[(size_t)tt * T + la];
        float tr_g = trans_lds[lp * T + la];
        gold += em_g * mt + ((tt > 0) ? tr_g * (mp * mt) : 0.f);
    }

    // ---- v init from alpha_0 = em_0, normalized by wave max ----
    float a0 = fb[lane];
    float A0 = a0;
    #pragma unroll
    for (int o = 32; o > 0; o >>= 1) A0 = fmaxf(A0, __shfl_xor(A0, o));
    float v = __expf(a0 - A0);
    float off = A0;

    // double-buffered Z-row loads (lane j holds row j)
    const unsigned short* zb = Zmat + ((size_t)b * G) * 64 * 64 + (size_t)lane * 64;
    uint4 cur[8], nxt[8];
    #pragma unroll
    for (int i = 0; i < 8; ++i) cur[i] = ((const uint4*)zb)[i];

    for (int g = 0; g < G; ++g) {
        if (g + 1 < G) {
            const uint4* zn = (const uint4*)(zb + (size_t)(g + 1) * 64 * 64);
            #pragma unroll
            for (int i = 0; i < 8; ++i) nxt[i] = zn[i];
        }
        const int buf = g & 1;
        bcast[buf][lane] = v;
        asm volatile("s_waitcnt lgkmcnt(0)" ::: "memory");
        f32x4 vb[16];
        #pragma unroll
        for (int q = 0; q < 16; ++q) vb[q] = ((const f32x4*)bcast[buf])[q];

        float acc = 0.f;
        #pragma unroll
        for (int i = 0; i < 8; ++i) {
            unsigned zz[4] = {cur[i].x, cur[i].y, cur[i].z, cur[i].w};
            #pragma unroll
            for (int d = 0; d < 4; ++d) {
                int k = i * 8 + d * 2;
                float f0 = __int_as_float(zz[d] << 16);
                float f1 = __int_as_float(zz[d] & 0xFFFF0000u);
                acc = fmaf(f0, vb[k >> 2][k & 3], acc);
                acc = fmaf(f1, vb[(k + 1) >> 2][(k + 1) & 3], acc);
            }
        }
        acc = fminf(fmaxf(acc, 0.f), 1e30f);
        // wave-max normalizer: v stays in [0,1], r strictly > 0
        float r = acc;
        #pragma unroll
        for (int o = 32; o > 0; o >>= 1) r = fmaxf(r, __shfl_xor(r, o));
        r = fmaxf(r, 1e-30f);
        v = acc / r;
        off += __logf(r) + (float)Kscale[b * G + g] * 0.69314718056f;
        #pragma unroll
        for (int i = 0; i < 8; ++i) cur[i] = nxt[i];
    }

    float sum = v;
    #pragma unroll
    for (int o = 32; o > 0; o >>= 1) sum += __shfl_xor(sum, o);
    float logZ = __logf(fmaxf(sum, 1e-30f)) + off;

    #pragma unroll
    for (int o = 32; o > 0; o >>= 1) gold += __shfl_xor(gold, o);

    if (lane == 0) res[b] = logZ - gold;
}

// ============================================================================
// Fallback: validated round-3 sequential kernel (used if ws too small)
// ============================================================================
__global__ __launch_bounds__(64, 1)
void crf_fwd_seq(const float* __restrict__ features,
                 const int*   __restrict__ labels,
                 const float* __restrict__ mask,
                 const float* __restrict__ transitions,
                 float*       __restrict__ ws)
{
    __shared__ float trans_lds[T * T];
    __shared__ __align__(16) _Float16 ea_lds[2][T];

    const int lane = threadIdx.x;
    const int b    = blockIdx.x;

    for (int i = 0; i < T; ++i)
        trans_lds[i * T + lane] = transitions[i * T + lane];
    __syncthreads();

    h2 etr[T / 2];
    #pragma unroll
    for (int k = 0; k < T / 2; ++k) {
        etr[k].x = (_Float16)__expf(trans_lds[(2 * k + 0) * T + lane]);
        etr[k].y = (_Float16)__expf(trans_lds[(2 * k + 1) * T + lane]);
    }

    const float* fb = features + (size_t)b * S * T;
    const float* mb = mask + (size_t)b * S;
    const int*   lb = labels + (size_t)b * S;

    float alpha = fb[lane];
    float gold_part = 0.f;
    float M = 0.f;

    float em_n1 = fb[1 * T + lane];
    float em_n2 = fb[2 * T + lane];
    float em_n3 = fb[3 * T + lane];

    int   lab_c = lb[lane];
    int   lab_p = lb[lane > 0 ? lane - 1 : 0];
    float m_c   = mb[lane];
    float m_p   = mb[lane > 0 ? lane - 1 : 0];

    for (int ch = 0; ch < S / T; ++ch) {
        const int base = ch * T;
        const int tt   = base + lane;

        const int   glab  = lab_c;
        const int   glabp = lab_p;
        const float gmc   = m_c;
        const float gmp   = m_p;
        const float mreg  = m_c;

        float em_g = fb[(size_t)tt * T + glab];
        float tr_g = trans_lds[glabp * T + glab];

        {
            int tn  = tt + T;  if (tn > S - 1) tn = S - 1;
            int tnp = tn - 1;  if (tnp < 0) tnp = 0;
            lab_c = lb[tn]; lab_p = lb[tnp];
            m_c   = mb[tn]; m_p   = mb[tnp];
        }

        const int i0 = (ch == 0) ? 1 : 0;
        #pragma unroll 4
        for (int i = i0; i < T; ++i) {
            const int t = base + i;
            float em = em_n1;
            em_n1 = em_n2; em_n2 = em_n3;
            int tn = t + 3; if (tn > S - 1) tn = S - 1;
            em_n3 = fb[tn * T + lane];

            float ea = __expf(alpha - M);
            ea_lds[t & 1][lane] = (_Float16)ea;
            asm volatile("s_waitcnt lgkmcnt(0)" ::: "memory");

            const uint4* ep = (const uint4*)&ea_lds[t & 1][0];
            float a0 = 0.f, a1 = 0.f, a2 = 0.f, a3 = 0.f;
            #pragma unroll
            for (int q = 0; q < 8; ++q) {
                uint4 r = ep[q];
                a0 = __builtin_amdgcn_fdot2(__builtin_bit_cast(h2, r.x), etr[4 * q + 0], a0, false);
                a1 = __builtin_amdgcn_fdot2(__builtin_bit_cast(h2, r.y), etr[4 * q + 1], a1, false);
                a2 = __builtin_amdgcn_fdot2(__builtin_bit_cast(h2, r.z), etr[4 * q + 2], a2, false);
                a3 = __builtin_amdgcn_fdot2(__builtin_bit_cast(h2, r.w), etr[4 * q + 3], a3, false);
            }
            float s = (a0 + a1) + (a2 + a3);

            float m_t = rdlane(mreg, i);
            float s1  = rdlane(s, 1);
            float em1 = rdlane(em, 1);
            float Mn  = M + __logf(s1) + em1;

            float val = M + __logf(s) + em;
            val = fmaxf(val, -1e30f);
            alpha = val * m_t + alpha * (1.f - m_t);
            M     = (m_t > 0.5f) ? Mn : M;
        }

        float valid = (tt > 0) ? 1.f : 0.f;
        gold_part += em_g * gmc + tr_g * (gmp * gmc) * valid;
    }

    float M2 = alpha;
    #pragma unroll
    for (int o = 32; o > 0; o >>= 1) M2 = fmaxf(M2, __shfl_xor(M2, o));
    float e2 = __expf(alpha - M2);
    #pragma unroll
    for (int o = 32; o > 0; o >>= 1) e2 += __shfl_xor(e2, o);
    float logZ = M2 + __logf(e2);

    #pragma unroll
    for (int o = 32; o > 0; o >>= 1) gold_part += __shfl_xor(gold_part, o);

    if (lane == 0) ws[b] = logZ - gold_part;
}

// Deterministic final mean over B=128 per-batch results.
__global__ __launch_bounds__(128)
void crf_reduce(const float* __restrict__ ws, float* __restrict__ out)
{
    const int tid = threadIdx.x;
    float v = ws[tid];
    #pragma unroll
    for (int o = 32; o > 0; o >>= 1) v += __shfl_xor(v, o);

    __shared__ float partial[2];
    if ((tid & 63) == 0) partial[tid >> 6] = v;
    __syncthreads();
    if (tid == 0) out[0] = (partial[0] + partial[1]) * (1.0f / (float)B);
}

extern "C" void kernel_launch(void* const* d_in, const int* in_sizes, int n_in,
                              void* d_out, int out_size, void* d_ws, size_t ws_size,
                              hipStream_t stream)
{
    const float* features    = (const float*)d_in[0]; // (B,S,T) f32
    const int*   labels      = (const int*)  d_in[1]; // (B,S) int
    const float* mask        = (const float*)d_in[2]; // (B,S) f32
    const float* transitions = (const float*)d_in[3]; // (T,T) f32
    float* out = (float*)d_out;

    const size_t zbytes = (size_t)B * G * 64 * 64 * sizeof(unsigned short); // 16 MB
    const size_t kbytes = (size_t)B * G * sizeof(int);
    const size_t need   = zbytes + kbytes + (size_t)B * sizeof(float);

    if (ws_size >= need) {
        unsigned short* Zmat = (unsigned short*)d_ws;
        int*   Ks  = (int*)((char*)d_ws + zbytes);
        float* res = (float*)((char*)d_ws + zbytes + kbytes);
        crf_chunk<<<dim3(B * G), dim3(64), 0, stream>>>(features, mask, transitions, Zmat, Ks);
        crf_apply<<<dim3(B), dim3(64), 0, stream>>>(features, labels, mask, transitions, Zmat, Ks, res);
        crf_reduce<<<dim3(1), dim3(128), 0, stream>>>(res, out);
    } else {
        float* res = (float*)d_ws;
        crf_fwd_seq<<<dim3(B), dim3(64), 0, stream>>>(features, labels, mask, transitions, res);
        crf_reduce<<<dim3(1), dim3(128), 0, stream>>>(res, out);
    }
}